// Round 1
// baseline (1145.419 us; speedup 1.0000x reference)
//
#include <hip/hip_runtime.h>
#include <hip/hip_bf16.h>
#include <math.h>

#define T_TOK 2048   // BATCH * SEQ
#define DM    1024
#define DI    2048
#define DS    16
#define DR    64
#define E96   96

__device__ __forceinline__ float silu_f(float x) {
    return x / (1.f + __expf(-x));
}
__device__ __forceinline__ float softplus_f(float x) {
    // jax.nn.softplus: log1p(exp(-|x|)) + max(x, 0)
    return log1pf(__expf(-fabsf(x))) + fmaxf(x, 0.f);
}

// C[M,N] = A[M,K] * B[N,K]^T  (both row-major, leading dims passed in).
// 128x128 tile, BK=8, 256 threads, 8x8 micro-tile per thread.
// EPI==1: C = softplus(C + bias[col])
template<int EPI>
__global__ __launch_bounds__(256) void sgemm128(
    const float* __restrict__ A, int lda,
    const float* __restrict__ B, int ldb,
    float* __restrict__ C, int ldc,
    int K, const float* __restrict__ bias)
{
    __shared__ float As[8][128];
    __shared__ float Bs[8][128];
    const int bm = blockIdx.y * 128, bn = blockIdx.x * 128;
    const int tid = threadIdx.x;
    const int lr = tid >> 1, lk = (tid & 1) * 4;
    const int tx = tid & 15, ty = tid >> 4;
    float acc[8][8] = {};
    const float* Ap = A + (size_t)(bm + lr) * lda + lk;
    const float* Bp = B + (size_t)(bn + lr) * ldb + lk;
    for (int k0 = 0; k0 < K; k0 += 8) {
        float4 av = *(const float4*)(Ap + k0);
        float4 bv = *(const float4*)(Bp + k0);
        __syncthreads();
        As[lk+0][lr] = av.x; As[lk+1][lr] = av.y; As[lk+2][lr] = av.z; As[lk+3][lr] = av.w;
        Bs[lk+0][lr] = bv.x; Bs[lk+1][lr] = bv.y; Bs[lk+2][lr] = bv.z; Bs[lk+3][lr] = bv.w;
        __syncthreads();
        #pragma unroll
        for (int k = 0; k < 8; ++k) {
            float a[8], b[8];
            *(float4*)&a[0] = *(const float4*)&As[k][ty*8];
            *(float4*)&a[4] = *(const float4*)&As[k][ty*8+4];
            *(float4*)&b[0] = *(const float4*)&Bs[k][tx*8];
            *(float4*)&b[4] = *(const float4*)&Bs[k][tx*8+4];
            #pragma unroll
            for (int i = 0; i < 8; ++i)
                #pragma unroll
                for (int j = 0; j < 8; ++j)
                    acc[i][j] = fmaf(a[i], b[j], acc[i][j]);
        }
    }
    #pragma unroll
    for (int i = 0; i < 8; ++i) {
        float* Crow = C + (size_t)(bm + ty*8 + i) * ldc + bn + tx*8;
        #pragma unroll
        for (int j = 0; j < 8; j += 4) {
            float4 v;
            float t0 = acc[i][j+0], t1 = acc[i][j+1], t2 = acc[i][j+2], t3 = acc[i][j+3];
            if (EPI == 1) {
                t0 = softplus_f(t0 + bias[bn + tx*8 + j+0]);
                t1 = softplus_f(t1 + bias[bn + tx*8 + j+1]);
                t2 = softplus_f(t2 + bias[bn + tx*8 + j+2]);
                t3 = softplus_f(t3 + bias[bn + tx*8 + j+3]);
            }
            v.x = t0; v.y = t1; v.z = t2; v.w = t3;
            *(float4*)&Crow[j] = v;
        }
    }
}

// depthwise causal conv (D_CONV=4) + silu.  xr is [T][4096], u half is cols [0,2048).
__global__ __launch_bounds__(256) void conv_silu_kernel(
    const float* __restrict__ xr, const float* __restrict__ Wc,
    const float* __restrict__ bc, float* __restrict__ u)
{
    int idx = blockIdx.x * 256 + threadIdx.x;   // = t*DI + d
    int d = idx & (DI - 1);
    int t = idx >> 11;
    int l = t & 1023;
    float4 w = *(const float4*)&Wc[d * 4];
    const float wj[4] = {w.x, w.y, w.z, w.w};
    float acc = bc[d];
    #pragma unroll
    for (int j = 0; j < 4; ++j) {
        int ll = l - 3 + j;
        if (ll >= 0) acc += xr[(size_t)(t - 3 + j) * 4096 + d] * wj[j];
    }
    u[idx] = silu_f(acc);
}

// dbc partial GEMM: dbc[dir][t][e] = sum_d u[t][d] * Wx[e][d]
// split-K: grid (32 rowblocks of 64, 8 k-chunks of 256, 2 dirs)
__global__ __launch_bounds__(256) void dbc_partial_kernel(
    const float* __restrict__ u, const float* __restrict__ fWx,
    const float* __restrict__ bWx, float* __restrict__ part)
{
    const int rb = blockIdx.x, ks = blockIdx.y, dir = blockIdx.z;
    const float* Wx = dir ? bWx : fWx;
    __shared__ float us[64][33];
    __shared__ float wsh[96][33];
    const int tid = threadIdx.x;
    const int t0 = rb * 64, k0 = ks * 256;
    const int r0 = (tid >> 5) * 8, c0 = (tid & 31) * 3;
    float acc[8][3] = {};
    for (int kk = 0; kk < 256; kk += 32) {
        __syncthreads();
        #pragma unroll
        for (int i = 0; i < 2; ++i) {
            int idx = tid + 256 * i;          // 0..511
            int r = idx >> 3, c4 = (idx & 7) * 4;
            float4 v = *(const float4*)&u[(size_t)(t0 + r) * DI + k0 + kk + c4];
            us[r][c4+0] = v.x; us[r][c4+1] = v.y; us[r][c4+2] = v.z; us[r][c4+3] = v.w;
        }
        #pragma unroll
        for (int i = 0; i < 3; ++i) {
            int idx = tid + 256 * i;          // 0..767
            int e = idx >> 3, c4 = (idx & 7) * 4;
            float4 v = *(const float4*)&Wx[(size_t)e * DI + k0 + kk + c4];
            wsh[e][c4+0] = v.x; wsh[e][c4+1] = v.y; wsh[e][c4+2] = v.z; wsh[e][c4+3] = v.w;
        }
        __syncthreads();
        #pragma unroll
        for (int k = 0; k < 32; ++k) {
            float w0 = wsh[c0][k], w1 = wsh[c0+1][k], w2 = wsh[c0+2][k];
            #pragma unroll
            for (int i = 0; i < 8; ++i) {
                float a = us[r0 + i][k];
                acc[i][0] = fmaf(a, w0, acc[i][0]);
                acc[i][1] = fmaf(a, w1, acc[i][1]);
                acc[i][2] = fmaf(a, w2, acc[i][2]);
            }
        }
    }
    float* pbase = part + (size_t)(dir * 8 + ks) * T_TOK * E96;
    #pragma unroll
    for (int i = 0; i < 8; ++i)
        #pragma unroll
        for (int j = 0; j < 3; ++j)
            pbase[(size_t)(t0 + r0 + i) * E96 + c0 + j] = acc[i][j];
}

__global__ __launch_bounds__(256) void dbc_reduce_kernel(
    const float* __restrict__ part, float* __restrict__ dbc)
{
    int idx = blockIdx.x * 256 + threadIdx.x;   // over 2*T*96
    int dir = idx / (T_TOK * E96);
    int rem = idx - dir * (T_TOK * E96);
    float s = 0.f;
    #pragma unroll
    for (int ks = 0; ks < 8; ++ks)
        s += part[(size_t)(dir * 8 + ks) * T_TOK * E96 + rem];
    dbc[idx] = s;
}

// selective scan, fused dA/dBu computation. 16 lanes per channel (one state each).
// grid: (DI/16, BATCH, dir), block 256 (=16 channels)
__global__ __launch_bounds__(256) void scan_kernel(
    const float* __restrict__ u,       // [T][DI]
    const float* __restrict__ delta,   // [2][T][DI]
    const float* __restrict__ dbc,     // [2][T][96]
    const float* __restrict__ fAlog, const float* __restrict__ fDp,
    const float* __restrict__ bAlog, const float* __restrict__ bDp,
    float* __restrict__ y)             // [T][DI] accumulated (atomic)
{
    const int tid = threadIdx.x;
    const int d   = blockIdx.x * 16 + (tid >> 4);
    const int n   = tid & 15;
    const int b   = blockIdx.y;
    const int dir = blockIdx.z;
    const float* Alog = dir ? bAlog : fAlog;
    const float* Dp   = dir ? bDp   : fDp;
    const float A  = -__expf(Alog[d * DS + n]);
    const float Dv = Dp[d];
    const float* dl_base = delta + (size_t)dir * T_TOK * DI;
    const float* bc_base = dbc   + (size_t)dir * T_TOK * E96;
    float h = 0.f;
    for (int s = 0; s < 1024; ++s) {
        int t  = dir ? (1023 - s) : s;
        int rt = (b << 10) + t;
        float dl = dl_base[(size_t)rt * DI + d];
        float uv = u[(size_t)rt * DI + d];
        float Bn = bc_base[(size_t)rt * E96 + 64 + n];
        float Cn = bc_base[(size_t)rt * E96 + 80 + n];
        h = __expf(dl * A) * h + dl * Bn * uv;
        float p = h * Cn;
        p += __shfl_xor(p, 1);
        p += __shfl_xor(p, 2);
        p += __shfl_xor(p, 4);
        p += __shfl_xor(p, 8);
        if (n == 0) atomicAdd(&y[(size_t)rt * DI + d], p + uv * Dv);
    }
}

// y *= 0.5 * silu(res)
__global__ __launch_bounds__(256) void combine_kernel(
    float* __restrict__ y, const float* __restrict__ xr)
{
    int idx = blockIdx.x * 256 + threadIdx.x;
    int d = idx & (DI - 1);
    int t = idx >> 11;
    float r = xr[(size_t)t * 4096 + DI + d];
    y[idx] = y[idx] * 0.5f * silu_f(r);
}

extern "C" void kernel_launch(void* const* d_in, const int* in_sizes, int n_in,
                              void* d_out, int out_size, void* d_ws, size_t ws_size,
                              hipStream_t stream)
{
    const float* x      = (const float*)d_in[0];
    const float* W_in   = (const float*)d_in[1];
    const float* W_conv = (const float*)d_in[2];
    const float* b_conv = (const float*)d_in[3];
    const float* W_out  = (const float*)d_in[4];
    const float* fA_log = (const float*)d_in[5];
    const float* fD     = (const float*)d_in[6];
    const float* fWx    = (const float*)d_in[7];
    const float* fWdt   = (const float*)d_in[8];
    const float* fbdt   = (const float*)d_in[9];
    const float* bA_log = (const float*)d_in[10];
    const float* bD     = (const float*)d_in[11];
    const float* bWx    = (const float*)d_in[12];
    const float* bWdt   = (const float*)d_in[13];
    const float* bbdt   = (const float*)d_in[14];

    char* ws = (char*)d_ws;
    float* xr    = (float*)(ws);                      // 2048*4096*4 = 32 MB
    float* u     = (float*)(ws + (32ull << 20));      // 16 MB
    float* part  = (float*)(ws + (48ull << 20));      // 2*8*2048*96*4 = 12.6 MB
    float* dbc   = (float*)(ws + (61ull << 20));      // 1.5 MB
    float* delta = (float*)(ws + (63ull << 20));      // 32 MB
    float* y     = (float*)(ws + (95ull << 20));      // 16 MB
    float* out   = (float*)d_out;

    // 1. xr = x @ W_in^T          (M=2048, N=4096, K=1024)
    sgemm128<0><<<dim3(4096/128, 2048/128), 256, 0, stream>>>(
        x, 1024, W_in, 1024, xr, 4096, 1024, nullptr);

    // 2. u = silu(causal_dwconv(xr[:, :2048]))
    conv_silu_kernel<<<(T_TOK * DI) / 256, 256, 0, stream>>>(xr, W_conv, b_conv, u);

    // 3. dbc[dir] = u @ Wx[dir]^T (split-K partials + reduce)
    dbc_partial_kernel<<<dim3(32, 8, 2), 256, 0, stream>>>(u, fWx, bWx, part);
    dbc_reduce_kernel<<<(2 * T_TOK * E96) / 256, 256, 0, stream>>>(part, dbc);

    // 4. delta[dir] = softplus(dt @ Wdt^T + bdt)   (M=2048, N=2048, K=64)
    sgemm128<1><<<dim3(2048/128, 2048/128), 256, 0, stream>>>(
        dbc, 96, fWdt, 64, delta, 2048, 64, fbdt);
    sgemm128<1><<<dim3(2048/128, 2048/128), 256, 0, stream>>>(
        dbc + (size_t)T_TOK * E96, 96, bWdt, 64, delta + (size_t)T_TOK * DI, 2048, 64, bbdt);

    // 5. y = 0; both direction scans accumulate (2 commutative adds -> deterministic)
    hipMemsetAsync(y, 0, (size_t)T_TOK * DI * sizeof(float), stream);
    scan_kernel<<<dim3(DI / 16, 2, 2), 256, 0, stream>>>(
        u, delta, dbc, fA_log, fD, bA_log, bD, y);

    // 6. y = (y_fwd + y_rev) * 0.5 * silu(res)
    combine_kernel<<<(T_TOK * DI) / 256, 256, 0, stream>>>(y, xr);

    // 7. out = y @ W_out^T        (M=2048, N=1024, K=2048)
    sgemm128<0><<<dim3(1024/128, 2048/128), 256, 0, stream>>>(
        y, 2048, W_out, 2048, out, 1024, 2048, nullptr);
}

// Round 2
// 845.047 us; speedup vs baseline: 1.3555x; 1.3555x over previous
//
#include <hip/hip_runtime.h>
#include <hip/hip_bf16.h>
#include <math.h>

#define T_TOK 2048   // BATCH * SEQ
#define DM    1024
#define DI    2048
#define DS    16
#define DR    64
#define E96   96
#define CH    128    // scan chunk length
#define NCH   8      // chunks per sequence (1024 / CH)

__device__ __forceinline__ float silu_f(float x) {
    return x / (1.f + __expf(-x));
}
__device__ __forceinline__ float softplus_f(float x) {
    return log1pf(__expf(-fabsf(x))) + fmaxf(x, 0.f);
}

// C[M,N] = A[M,K] * B[N,K]^T  (both row-major).
// 128x128 tile, BK=8, 256 threads, 8x8 micro-tile per thread.
// EPI==1: C = softplus(C + bias[col])
template<int EPI>
__global__ __launch_bounds__(256) void sgemm128(
    const float* __restrict__ A, int lda,
    const float* __restrict__ B, int ldb,
    float* __restrict__ C, int ldc,
    int K, const float* __restrict__ bias)
{
    __shared__ float As[8][128];
    __shared__ float Bs[8][128];
    const int bm = blockIdx.y * 128, bn = blockIdx.x * 128;
    const int tid = threadIdx.x;
    const int lr = tid >> 1, lk = (tid & 1) * 4;
    const int tx = tid & 15, ty = tid >> 4;
    float acc[8][8] = {};
    const float* Ap = A + (size_t)(bm + lr) * lda + lk;
    const float* Bp = B + (size_t)(bn + lr) * ldb + lk;
    for (int k0 = 0; k0 < K; k0 += 8) {
        float4 av = *(const float4*)(Ap + k0);
        float4 bv = *(const float4*)(Bp + k0);
        __syncthreads();
        As[lk+0][lr] = av.x; As[lk+1][lr] = av.y; As[lk+2][lr] = av.z; As[lk+3][lr] = av.w;
        Bs[lk+0][lr] = bv.x; Bs[lk+1][lr] = bv.y; Bs[lk+2][lr] = bv.z; Bs[lk+3][lr] = bv.w;
        __syncthreads();
        #pragma unroll
        for (int k = 0; k < 8; ++k) {
            float a[8], b[8];
            *(float4*)&a[0] = *(const float4*)&As[k][ty*8];
            *(float4*)&a[4] = *(const float4*)&As[k][ty*8+4];
            *(float4*)&b[0] = *(const float4*)&Bs[k][tx*8];
            *(float4*)&b[4] = *(const float4*)&Bs[k][tx*8+4];
            #pragma unroll
            for (int i = 0; i < 8; ++i)
                #pragma unroll
                for (int j = 0; j < 8; ++j)
                    acc[i][j] = fmaf(a[i], b[j], acc[i][j]);
        }
    }
    #pragma unroll
    for (int i = 0; i < 8; ++i) {
        float* Crow = C + (size_t)(bm + ty*8 + i) * ldc + bn + tx*8;
        #pragma unroll
        for (int j = 0; j < 8; j += 4) {
            float4 v;
            float t0 = acc[i][j+0], t1 = acc[i][j+1], t2 = acc[i][j+2], t3 = acc[i][j+3];
            if (EPI == 1) {
                t0 = softplus_f(t0 + bias[bn + tx*8 + j+0]);
                t1 = softplus_f(t1 + bias[bn + tx*8 + j+1]);
                t2 = softplus_f(t2 + bias[bn + tx*8 + j+2]);
                t3 = softplus_f(t3 + bias[bn + tx*8 + j+3]);
            }
            v.x = t0; v.y = t1; v.z = t2; v.w = t3;
            *(float4*)&Crow[j] = v;
        }
    }
}

// depthwise causal conv (D_CONV=4) + silu.  xr is [T][4096], u half is cols [0,2048).
__global__ __launch_bounds__(256) void conv_silu_kernel(
    const float* __restrict__ xr, const float* __restrict__ Wc,
    const float* __restrict__ bc, float* __restrict__ u)
{
    int idx = blockIdx.x * 256 + threadIdx.x;   // = t*DI + d
    int d = idx & (DI - 1);
    int t = idx >> 11;
    int l = t & 1023;
    float4 w = *(const float4*)&Wc[d * 4];
    const float wj[4] = {w.x, w.y, w.z, w.w};
    float acc = bc[d];
    #pragma unroll
    for (int j = 0; j < 4; ++j) {
        int ll = l - 3 + j;
        if (ll >= 0) acc += xr[(size_t)(t - 3 + j) * 4096 + d] * wj[j];
    }
    u[idx] = silu_f(acc);
}

// dbc partial GEMM: dbc[dir][t][e] = sum_d u[t][d] * Wx[e][d]
__global__ __launch_bounds__(256) void dbc_partial_kernel(
    const float* __restrict__ u, const float* __restrict__ fWx,
    const float* __restrict__ bWx, float* __restrict__ part)
{
    const int rb = blockIdx.x, ks = blockIdx.y, dir = blockIdx.z;
    const float* Wx = dir ? bWx : fWx;
    __shared__ float us[64][33];
    __shared__ float wsh[96][33];
    const int tid = threadIdx.x;
    const int t0 = rb * 64, k0 = ks * 256;
    const int r0 = (tid >> 5) * 8, c0 = (tid & 31) * 3;
    float acc[8][3] = {};
    for (int kk = 0; kk < 256; kk += 32) {
        __syncthreads();
        #pragma unroll
        for (int i = 0; i < 2; ++i) {
            int idx = tid + 256 * i;
            int r = idx >> 3, c4 = (idx & 7) * 4;
            float4 v = *(const float4*)&u[(size_t)(t0 + r) * DI + k0 + kk + c4];
            us[r][c4+0] = v.x; us[r][c4+1] = v.y; us[r][c4+2] = v.z; us[r][c4+3] = v.w;
        }
        #pragma unroll
        for (int i = 0; i < 3; ++i) {
            int idx = tid + 256 * i;
            int e = idx >> 3, c4 = (idx & 7) * 4;
            float4 v = *(const float4*)&Wx[(size_t)e * DI + k0 + kk + c4];
            wsh[e][c4+0] = v.x; wsh[e][c4+1] = v.y; wsh[e][c4+2] = v.z; wsh[e][c4+3] = v.w;
        }
        __syncthreads();
        #pragma unroll
        for (int k = 0; k < 32; ++k) {
            float w0 = wsh[c0][k], w1 = wsh[c0+1][k], w2 = wsh[c0+2][k];
            #pragma unroll
            for (int i = 0; i < 8; ++i) {
                float a = us[r0 + i][k];
                acc[i][0] = fmaf(a, w0, acc[i][0]);
                acc[i][1] = fmaf(a, w1, acc[i][1]);
                acc[i][2] = fmaf(a, w2, acc[i][2]);
            }
        }
    }
    float* pbase = part + (size_t)(dir * 8 + ks) * T_TOK * E96;
    #pragma unroll
    for (int i = 0; i < 8; ++i)
        #pragma unroll
        for (int j = 0; j < 3; ++j)
            pbase[(size_t)(t0 + r0 + i) * E96 + c0 + j] = acc[i][j];
}

__global__ __launch_bounds__(256) void dbc_reduce_kernel(
    const float* __restrict__ part, float* __restrict__ dbc)
{
    int idx = blockIdx.x * 256 + threadIdx.x;
    int dir = idx / (T_TOK * E96);
    int rem = idx - dir * (T_TOK * E96);
    float s = 0.f;
    #pragma unroll
    for (int ks = 0; ks < 8; ++ks)
        s += part[(size_t)(dir * 8 + ks) * T_TOK * E96 + rem];
    dbc[idx] = s;
}

// ---------- chunked scan: 3 passes ----------
// lane = (channel, state): d = bx*16 + tid>>4, n = tid&15.
// blockIdx.y = chunk (in SCAN order), blockIdx.z = dir*2 + b.

// pass1: local scan from h=0 within chunk; emit P = prod(dA) and local h.
// layout of Pb/Hb: [z][d][n][c]  (c contiguous for pass2)
__global__ __launch_bounds__(256) void scan_pass1(
    const float* __restrict__ u, const float* __restrict__ delta,
    const float* __restrict__ dbc,
    const float* __restrict__ fAlog, const float* __restrict__ bAlog,
    float* __restrict__ Pb, float* __restrict__ Hb)
{
    const int tid = threadIdx.x;
    const int d   = blockIdx.x * 16 + (tid >> 4);
    const int n   = tid & 15;
    const int c   = blockIdx.y;
    const int z   = blockIdx.z;
    const int dir = z >> 1, b = z & 1;
    const float* Alog = dir ? bAlog : fAlog;
    const float A = -__expf(Alog[d * DS + n]);
    const float* dl_base = delta + (size_t)dir * T_TOK * DI;
    const float* bc_base = dbc   + (size_t)dir * T_TOK * E96;
    float P = 1.f, h = 0.f;
    for (int s = 0; s < CH; ++s) {
        int p  = c * CH + s;
        int l  = dir ? (1023 - p) : p;
        int rt = (b << 10) + l;
        float dl = dl_base[(size_t)rt * DI + d];
        float uv = u[(size_t)rt * DI + d];
        float Bn = bc_base[(size_t)rt * E96 + 64 + n];
        float a  = __expf(dl * A);
        h = a * h + dl * Bn * uv;
        P *= a;
    }
    size_t o = ((size_t)(z * DI + d) * DS + n) * NCH + c;
    Pb[o] = P;
    Hb[o] = h;
}

// pass2: combine chunks sequentially; store each chunk's true initial h
// IN PLACE over Pb.
__global__ __launch_bounds__(256) void scan_pass2(
    float* __restrict__ Pb, const float* __restrict__ Hb)
{
    int idx = blockIdx.x * 256 + threadIdx.x;   // (z*DI+d)*DS + n
    size_t base = (size_t)idx * NCH;
    float h = 0.f;
    #pragma unroll
    for (int c = 0; c < NCH; ++c) {
        float P  = Pb[base + c];
        float hl = Hb[base + c];
        Pb[base + c] = h;          // h_in for chunk c
        h = P * h + hl;
    }
}

// pass3: re-run chunk with correct initial h, emit y (atomic: both dirs accumulate)
__global__ __launch_bounds__(256) void scan_pass3(
    const float* __restrict__ u, const float* __restrict__ delta,
    const float* __restrict__ dbc,
    const float* __restrict__ fAlog, const float* __restrict__ fDp,
    const float* __restrict__ bAlog, const float* __restrict__ bDp,
    const float* __restrict__ Hin, float* __restrict__ y)
{
    const int tid = threadIdx.x;
    const int d   = blockIdx.x * 16 + (tid >> 4);
    const int n   = tid & 15;
    const int c   = blockIdx.y;
    const int z   = blockIdx.z;
    const int dir = z >> 1, b = z & 1;
    const float* Alog = dir ? bAlog : fAlog;
    const float* Dp   = dir ? bDp   : fDp;
    const float A  = -__expf(Alog[d * DS + n]);
    const float Dv = Dp[d];
    const float* dl_base = delta + (size_t)dir * T_TOK * DI;
    const float* bc_base = dbc   + (size_t)dir * T_TOK * E96;
    float h = Hin[((size_t)(z * DI + d) * DS + n) * NCH + c];
    for (int s = 0; s < CH; ++s) {
        int p  = c * CH + s;
        int l  = dir ? (1023 - p) : p;
        int rt = (b << 10) + l;
        float dl = dl_base[(size_t)rt * DI + d];
        float uv = u[(size_t)rt * DI + d];
        float Bn = bc_base[(size_t)rt * E96 + 64 + n];
        float Cn = bc_base[(size_t)rt * E96 + 80 + n];
        float a  = __expf(dl * A);
        h = a * h + dl * Bn * uv;
        float pv = h * Cn;
        pv += __shfl_xor(pv, 1);
        pv += __shfl_xor(pv, 2);
        pv += __shfl_xor(pv, 4);
        pv += __shfl_xor(pv, 8);
        if (n == 0) atomicAdd(&y[(size_t)rt * DI + d], pv + uv * Dv);
    }
}

// y *= 0.5 * silu(res)
__global__ __launch_bounds__(256) void combine_kernel(
    float* __restrict__ y, const float* __restrict__ xr)
{
    int idx = blockIdx.x * 256 + threadIdx.x;
    int d = idx & (DI - 1);
    int t = idx >> 11;
    float r = xr[(size_t)t * 4096 + DI + d];
    y[idx] = y[idx] * 0.5f * silu_f(r);
}

extern "C" void kernel_launch(void* const* d_in, const int* in_sizes, int n_in,
                              void* d_out, int out_size, void* d_ws, size_t ws_size,
                              hipStream_t stream)
{
    const float* x      = (const float*)d_in[0];
    const float* W_in   = (const float*)d_in[1];
    const float* W_conv = (const float*)d_in[2];
    const float* b_conv = (const float*)d_in[3];
    const float* W_out  = (const float*)d_in[4];
    const float* fA_log = (const float*)d_in[5];
    const float* fD     = (const float*)d_in[6];
    const float* fWx    = (const float*)d_in[7];
    const float* fWdt   = (const float*)d_in[8];
    const float* fbdt   = (const float*)d_in[9];
    const float* bA_log = (const float*)d_in[10];
    const float* bD     = (const float*)d_in[11];
    const float* bWx    = (const float*)d_in[12];
    const float* bWdt   = (const float*)d_in[13];
    const float* bbdt   = (const float*)d_in[14];

    char* ws = (char*)d_ws;
    float* xr    = (float*)(ws);                      // [0,32M)
    float* u     = (float*)(ws + (32ull << 20));      // [32,48M)
    float* dbc   = (float*)(ws + (48ull << 20));      // [48,49.6M) 1.6MB
    float* delta = (float*)(ws + (50ull << 20));      // [50,82M) 32MB
    float* part  = (float*)(ws + (50ull << 20));      // aliased under delta (12.6MB)
    float* y     = (float*)(ws + (82ull << 20));      // [82,98M)
    float* Pb    = (float*)(ws + (98ull << 20));      // [98,102M) 4MB
    float* Hb    = (float*)(ws + (102ull << 20));     // [102,106M) 4MB
    float* out   = (float*)d_out;

    // 1. xr = x @ W_in^T          (M=2048, N=4096, K=1024)
    sgemm128<0><<<dim3(4096/128, 2048/128), 256, 0, stream>>>(
        x, 1024, W_in, 1024, xr, 4096, 1024, nullptr);

    // 2. u = silu(causal_dwconv(xr[:, :2048]))
    conv_silu_kernel<<<(T_TOK * DI) / 256, 256, 0, stream>>>(xr, W_conv, b_conv, u);

    // 3. dbc[dir] = u @ Wx[dir]^T
    dbc_partial_kernel<<<dim3(32, 8, 2), 256, 0, stream>>>(u, fWx, bWx, part);
    dbc_reduce_kernel<<<(2 * T_TOK * E96) / 256, 256, 0, stream>>>(part, dbc);

    // 4. delta[dir] = softplus(dt @ Wdt^T + bdt)  (overwrites part alias)
    sgemm128<1><<<dim3(2048/128, 2048/128), 256, 0, stream>>>(
        dbc, 96, fWdt, 64, delta, 2048, 64, fbdt);
    sgemm128<1><<<dim3(2048/128, 2048/128), 256, 0, stream>>>(
        dbc + (size_t)T_TOK * E96, 96, bWdt, 64, delta + (size_t)T_TOK * DI, 2048, 64, bbdt);

    // 5. chunked scan (3 passes), both dirs accumulate into y
    scan_pass1<<<dim3(DI / 16, NCH, 4), 256, 0, stream>>>(
        u, delta, dbc, fA_log, bA_log, Pb, Hb);
    scan_pass2<<<(4 * DI * DS) / 256, 256, 0, stream>>>(Pb, Hb);
    hipMemsetAsync(y, 0, (size_t)T_TOK * DI * sizeof(float), stream);
    scan_pass3<<<dim3(DI / 16, NCH, 4), 256, 0, stream>>>(
        u, delta, dbc, fA_log, fD, bA_log, bD, Pb, y);

    // 6. y = (y_fwd + y_rev) * 0.5 * silu(res)
    combine_kernel<<<(T_TOK * DI) / 256, 256, 0, stream>>>(y, xr);

    // 7. out = y @ W_out^T        (M=2048, N=1024, K=2048)
    sgemm128<0><<<dim3(1024/128, 2048/128), 256, 0, stream>>>(
        y, 2048, W_out, 2048, out, 1024, 2048, nullptr);
}

// Round 3
// 469.466 us; speedup vs baseline: 2.4398x; 1.8000x over previous
//
#include <hip/hip_runtime.h>
#include <hip/hip_bf16.h>
#include <math.h>

#define T_TOK 2048   // BATCH * SEQ
#define DM    1024
#define DI    2048
#define DS    16
#define DR    64
#define E96   96
#define CH    128    // scan chunk length
#define NCH   8      // chunks per sequence (1024 / CH)

typedef __attribute__((ext_vector_type(8))) short bf16x8;
typedef __attribute__((ext_vector_type(4))) float f32x4;

__device__ __forceinline__ float silu_f(float x) {
    return x / (1.f + __expf(-x));
}
__device__ __forceinline__ float softplus_f(float x) {
    return log1pf(__expf(-fabsf(x))) + fmaxf(x, 0.f);
}
__device__ __forceinline__ unsigned short f2bf(float f) {
    unsigned int u = __float_as_uint(f);
    u = (u + 0x7fffu + ((u >> 16) & 1u)) >> 16;   // round-to-nearest-even
    return (unsigned short)u;
}
__device__ __forceinline__ float bf2f(unsigned short h) {
    return __uint_as_float(((unsigned int)h) << 16);
}
__device__ __forceinline__ void gload16(const unsigned short* g, unsigned short* l) {
    __builtin_amdgcn_global_load_lds((const __attribute__((address_space(1))) void*)g,
                                     (__attribute__((address_space(3))) void*)l, 16, 0, 0);
}

// fp32 -> (hi, lo) bf16 split, vectorized by 4
__global__ __launch_bounds__(256) void split_kernel(
    const float* __restrict__ in, unsigned short* __restrict__ hi,
    unsigned short* __restrict__ lo, int n4)
{
    int i = blockIdx.x * 256 + threadIdx.x;
    if (i >= n4) return;
    float4 v = ((const float4*)in)[i];
    ushort4 h, l;
    h.x = f2bf(v.x); l.x = f2bf(v.x - bf2f(h.x));
    h.y = f2bf(v.y); l.y = f2bf(v.y - bf2f(h.y));
    h.z = f2bf(v.z); l.z = f2bf(v.z - bf2f(h.z));
    h.w = f2bf(v.w); l.w = f2bf(v.w - bf2f(h.w));
    ((ushort4*)hi)[i] = h;
    ((ushort4*)lo)[i] = l;
}

// Split-bf16 MFMA GEMM: C[M,N] = A[M,K] * B[N,K]^T  (3-term: hh + lh + hl).
// 128x128 tile, BK=32, 256 threads = 4 waves (2x2), each wave 64x64 (4x4 frags).
// LDS element layout: Ah [128][32] @0, Al @4096, Bh @8192, Bl @12288,
// with k-slot XOR swizzle slot' = slot ^ ((row>>1)&3).
// EPI 0: C = acc (store).  EPI 2: atomicAdd (split-K partials, C pre-zeroed).
template<int EPI>
__global__ __launch_bounds__(256, 2) void mgemm128(
    const unsigned short* __restrict__ Ah, const unsigned short* __restrict__ Al, int lda,
    const unsigned short* __restrict__ Bh, const unsigned short* __restrict__ Bl, int ldb,
    float* __restrict__ C, int ldc, int K)
{
    __shared__ unsigned short lds[16384];    // 32 KB
    const int tid = threadIdx.x;
    const int wid = tid >> 6, lane = tid & 63;
    const int wm = wid >> 1, wn = wid & 1;
    const int bm = blockIdx.y * 128, bn = blockIdx.x * 128;
    const int klen = K / gridDim.z;
    const int kbeg = blockIdx.z * klen, kend = kbeg + klen;

    // staging geometry: wave stages rows [wid*32, wid*32+32) of each tile,
    // 2 instructions of 16 rows (1 KB) each; lane l -> row += l>>2, slot-pos l&3.
    const int r0  = wid * 32 + (lane >> 2);
    const int r1  = r0 + 16;
    const int sp  = lane & 3;
    const int ks0 = sp ^ ((r0 >> 1) & 3);
    const int ks1 = sp ^ ((r1 >> 1) & 3);
    const size_t ga0 = (size_t)(bm + r0) * lda + ks0 * 8;
    const size_t ga1 = (size_t)(bm + r1) * lda + ks1 * 8;
    const size_t gb0 = (size_t)(bn + r0) * ldb + ks0 * 8;
    const size_t gb1 = (size_t)(bn + r1) * ldb + ks1 * 8;
    unsigned short* lw0 = lds + wid * 1024;        // j=0 chunk (16 rows)
    unsigned short* lw1 = lds + wid * 1024 + 512;  // j=1 chunk

    // fragment read offsets (swizzled)
    const int ln = lane & 15, ls = lane >> 4;
    int offA[4], offB[4];
    #pragma unroll
    for (int f = 0; f < 4; ++f) {
        int ra = wm * 64 + f * 16 + ln;
        int rb = wn * 64 + f * 16 + ln;
        offA[f] = ra * 32 + (ls ^ ((ra >> 1) & 3)) * 8;
        offB[f] = rb * 32 + (ls ^ ((rb >> 1) & 3)) * 8;
    }

    f32x4 acc[4][4] = {};
    for (int k0 = kbeg; k0 < kend; k0 += 32) {
        gload16(Ah + ga0 + k0, lw0);
        gload16(Ah + ga1 + k0, lw1);
        gload16(Al + ga0 + k0, lw0 + 4096);
        gload16(Al + ga1 + k0, lw1 + 4096);
        gload16(Bh + gb0 + k0, lw0 + 8192);
        gload16(Bh + gb1 + k0, lw1 + 8192);
        gload16(Bl + gb0 + k0, lw0 + 12288);
        gload16(Bl + gb1 + k0, lw1 + 12288);
        __syncthreads();
        bf16x8 ah[4], al[4], bh[4], bl[4];
        #pragma unroll
        for (int f = 0; f < 4; ++f) {
            ah[f] = *(const bf16x8*)&lds[offA[f]];
            al[f] = *(const bf16x8*)&lds[4096 + offA[f]];
            bh[f] = *(const bf16x8*)&lds[8192 + offB[f]];
            bl[f] = *(const bf16x8*)&lds[12288 + offB[f]];
        }
        #pragma unroll
        for (int i = 0; i < 4; ++i)
            #pragma unroll
            for (int j = 0; j < 4; ++j) {
                acc[i][j] = __builtin_amdgcn_mfma_f32_16x16x32_bf16(ah[i], bh[j], acc[i][j], 0, 0, 0);
                acc[i][j] = __builtin_amdgcn_mfma_f32_16x16x32_bf16(al[i], bh[j], acc[i][j], 0, 0, 0);
                acc[i][j] = __builtin_amdgcn_mfma_f32_16x16x32_bf16(ah[i], bl[j], acc[i][j], 0, 0, 0);
            }
        __syncthreads();
    }

    #pragma unroll
    for (int i = 0; i < 4; ++i) {
        int crow0 = bm + wm * 64 + i * 16 + ls * 4;
        #pragma unroll
        for (int j = 0; j < 4; ++j) {
            int ccol = bn + wn * 64 + j * 16 + ln;
            #pragma unroll
            for (int r = 0; r < 4; ++r) {
                float v = acc[i][j][r];
                if (EPI == 2) atomicAdd(&C[(size_t)(crow0 + r) * ldc + ccol], v);
                else          C[(size_t)(crow0 + r) * ldc + ccol] = v;
            }
        }
    }
}

// fp32 GEMM for the small K=64 delta matmuls.  C = softplus(A*B^T + bias) if EPI==1.
template<int EPI>
__global__ __launch_bounds__(256) void sgemm128(
    const float* __restrict__ A, int lda,
    const float* __restrict__ B, int ldb,
    float* __restrict__ C, int ldc,
    int K, const float* __restrict__ bias)
{
    __shared__ float As[8][128];
    __shared__ float Bs[8][128];
    const int bm = blockIdx.y * 128, bn = blockIdx.x * 128;
    const int tid = threadIdx.x;
    const int lr = tid >> 1, lk = (tid & 1) * 4;
    const int tx = tid & 15, ty = tid >> 4;
    float acc[8][8] = {};
    const float* Ap = A + (size_t)(bm + lr) * lda + lk;
    const float* Bp = B + (size_t)(bn + lr) * ldb + lk;
    for (int k0 = 0; k0 < K; k0 += 8) {
        float4 av = *(const float4*)(Ap + k0);
        float4 bv = *(const float4*)(Bp + k0);
        __syncthreads();
        As[lk+0][lr] = av.x; As[lk+1][lr] = av.y; As[lk+2][lr] = av.z; As[lk+3][lr] = av.w;
        Bs[lk+0][lr] = bv.x; Bs[lk+1][lr] = bv.y; Bs[lk+2][lr] = bv.z; Bs[lk+3][lr] = bv.w;
        __syncthreads();
        #pragma unroll
        for (int k = 0; k < 8; ++k) {
            float a[8], b[8];
            *(float4*)&a[0] = *(const float4*)&As[k][ty*8];
            *(float4*)&a[4] = *(const float4*)&As[k][ty*8+4];
            *(float4*)&b[0] = *(const float4*)&Bs[k][tx*8];
            *(float4*)&b[4] = *(const float4*)&Bs[k][tx*8+4];
            #pragma unroll
            for (int i = 0; i < 8; ++i)
                #pragma unroll
                for (int j = 0; j < 8; ++j)
                    acc[i][j] = fmaf(a[i], b[j], acc[i][j]);
        }
    }
    #pragma unroll
    for (int i = 0; i < 8; ++i) {
        float* Crow = C + (size_t)(bm + ty*8 + i) * ldc + bn + tx*8;
        #pragma unroll
        for (int j = 0; j < 8; j += 4) {
            float4 v;
            float t0 = acc[i][j+0], t1 = acc[i][j+1], t2 = acc[i][j+2], t3 = acc[i][j+3];
            if (EPI == 1) {
                t0 = softplus_f(t0 + bias[bn + tx*8 + j+0]);
                t1 = softplus_f(t1 + bias[bn + tx*8 + j+1]);
                t2 = softplus_f(t2 + bias[bn + tx*8 + j+2]);
                t3 = softplus_f(t3 + bias[bn + tx*8 + j+3]);
            }
            v.x = t0; v.y = t1; v.z = t2; v.w = t3;
            *(float4*)&Crow[j] = v;
        }
    }
}

// depthwise causal conv (D_CONV=4) + silu.
__global__ __launch_bounds__(256) void conv_silu_kernel(
    const float* __restrict__ xr, const float* __restrict__ Wc,
    const float* __restrict__ bc, float* __restrict__ u)
{
    int idx = blockIdx.x * 256 + threadIdx.x;
    int d = idx & (DI - 1);
    int t = idx >> 11;
    int l = t & 1023;
    float4 w = *(const float4*)&Wc[d * 4];
    const float wj[4] = {w.x, w.y, w.z, w.w};
    float acc = bc[d];
    #pragma unroll
    for (int j = 0; j < 4; ++j) {
        int ll = l - 3 + j;
        if (ll >= 0) acc += xr[(size_t)(t - 3 + j) * 4096 + d] * wj[j];
    }
    u[idx] = silu_f(acc);
}

// dbc partial GEMM (fp32 split-K)
__global__ __launch_bounds__(256) void dbc_partial_kernel(
    const float* __restrict__ u, const float* __restrict__ fWx,
    const float* __restrict__ bWx, float* __restrict__ part)
{
    const int rb = blockIdx.x, ks = blockIdx.y, dir = blockIdx.z;
    const float* Wx = dir ? bWx : fWx;
    __shared__ float us[64][33];
    __shared__ float wsh[96][33];
    const int tid = threadIdx.x;
    const int t0 = rb * 64, k0 = ks * 256;
    const int r0 = (tid >> 5) * 8, c0 = (tid & 31) * 3;
    float acc[8][3] = {};
    for (int kk = 0; kk < 256; kk += 32) {
        __syncthreads();
        #pragma unroll
        for (int i = 0; i < 2; ++i) {
            int idx = tid + 256 * i;
            int r = idx >> 3, c4 = (idx & 7) * 4;
            float4 v = *(const float4*)&u[(size_t)(t0 + r) * DI + k0 + kk + c4];
            us[r][c4+0] = v.x; us[r][c4+1] = v.y; us[r][c4+2] = v.z; us[r][c4+3] = v.w;
        }
        #pragma unroll
        for (int i = 0; i < 3; ++i) {
            int idx = tid + 256 * i;
            int e = idx >> 3, c4 = (idx & 7) * 4;
            float4 v = *(const float4*)&Wx[(size_t)e * DI + k0 + kk + c4];
            wsh[e][c4+0] = v.x; wsh[e][c4+1] = v.y; wsh[e][c4+2] = v.z; wsh[e][c4+3] = v.w;
        }
        __syncthreads();
        #pragma unroll
        for (int k = 0; k < 32; ++k) {
            float w0 = wsh[c0][k], w1 = wsh[c0+1][k], w2 = wsh[c0+2][k];
            #pragma unroll
            for (int i = 0; i < 8; ++i) {
                float a = us[r0 + i][k];
                acc[i][0] = fmaf(a, w0, acc[i][0]);
                acc[i][1] = fmaf(a, w1, acc[i][1]);
                acc[i][2] = fmaf(a, w2, acc[i][2]);
            }
        }
    }
    float* pbase = part + (size_t)(dir * 8 + ks) * T_TOK * E96;
    #pragma unroll
    for (int i = 0; i < 8; ++i)
        #pragma unroll
        for (int j = 0; j < 3; ++j)
            pbase[(size_t)(t0 + r0 + i) * E96 + c0 + j] = acc[i][j];
}

__global__ __launch_bounds__(256) void dbc_reduce_kernel(
    const float* __restrict__ part, float* __restrict__ dbc)
{
    int idx = blockIdx.x * 256 + threadIdx.x;
    int dir = idx / (T_TOK * E96);
    int rem = idx - dir * (T_TOK * E96);
    float s = 0.f;
    #pragma unroll
    for (int ks = 0; ks < 8; ++ks)
        s += part[(size_t)(dir * 8 + ks) * T_TOK * E96 + rem];
    dbc[idx] = s;
}

// ---------- chunked scan: 3 passes ----------
__global__ __launch_bounds__(256) void scan_pass1(
    const float* __restrict__ u, const float* __restrict__ delta,
    const float* __restrict__ dbc,
    const float* __restrict__ fAlog, const float* __restrict__ bAlog,
    float* __restrict__ Pb, float* __restrict__ Hb)
{
    const int tid = threadIdx.x;
    const int d   = blockIdx.x * 16 + (tid >> 4);
    const int n   = tid & 15;
    const int c   = blockIdx.y;
    const int z   = blockIdx.z;
    const int dir = z >> 1, b = z & 1;
    const float* Alog = dir ? bAlog : fAlog;
    const float A = -__expf(Alog[d * DS + n]);
    const float* dl_base = delta + (size_t)dir * T_TOK * DI;
    const float* bc_base = dbc   + (size_t)dir * T_TOK * E96;
    float P = 1.f, h = 0.f;
    for (int s = 0; s < CH; ++s) {
        int p  = c * CH + s;
        int l  = dir ? (1023 - p) : p;
        int rt = (b << 10) + l;
        float dl = dl_base[(size_t)rt * DI + d];
        float uv = u[(size_t)rt * DI + d];
        float Bn = bc_base[(size_t)rt * E96 + 64 + n];
        float a  = __expf(dl * A);
        h = a * h + dl * Bn * uv;
        P *= a;
    }
    size_t o = ((size_t)(z * DI + d) * DS + n) * NCH + c;
    Pb[o] = P;
    Hb[o] = h;
}

__global__ __launch_bounds__(256) void scan_pass2(
    float* __restrict__ Pb, const float* __restrict__ Hb)
{
    int idx = blockIdx.x * 256 + threadIdx.x;
    size_t base = (size_t)idx * NCH;
    float h = 0.f;
    #pragma unroll
    for (int c = 0; c < NCH; ++c) {
        float P  = Pb[base + c];
        float hl = Hb[base + c];
        Pb[base + c] = h;
        h = P * h + hl;
    }
}

__global__ __launch_bounds__(256) void scan_pass3(
    const float* __restrict__ u, const float* __restrict__ delta,
    const float* __restrict__ dbc,
    const float* __restrict__ fAlog, const float* __restrict__ fDp,
    const float* __restrict__ bAlog, const float* __restrict__ bDp,
    const float* __restrict__ Hin, float* __restrict__ y)
{
    const int tid = threadIdx.x;
    const int d   = blockIdx.x * 16 + (tid >> 4);
    const int n   = tid & 15;
    const int c   = blockIdx.y;
    const int z   = blockIdx.z;
    const int dir = z >> 1, b = z & 1;
    const float* Alog = dir ? bAlog : fAlog;
    const float* Dp   = dir ? bDp   : fDp;
    const float A  = -__expf(Alog[d * DS + n]);
    const float Dv = Dp[d];
    const float* dl_base = delta + (size_t)dir * T_TOK * DI;
    const float* bc_base = dbc   + (size_t)dir * T_TOK * E96;
    float h = Hin[((size_t)(z * DI + d) * DS + n) * NCH + c];
    for (int s = 0; s < CH; ++s) {
        int p  = c * CH + s;
        int l  = dir ? (1023 - p) : p;
        int rt = (b << 10) + l;
        float dl = dl_base[(size_t)rt * DI + d];
        float uv = u[(size_t)rt * DI + d];
        float Bn = bc_base[(size_t)rt * E96 + 64 + n];
        float Cn = bc_base[(size_t)rt * E96 + 80 + n];
        float a  = __expf(dl * A);
        h = a * h + dl * Bn * uv;
        float pv = h * Cn;
        pv += __shfl_xor(pv, 1);
        pv += __shfl_xor(pv, 2);
        pv += __shfl_xor(pv, 4);
        pv += __shfl_xor(pv, 8);
        if (n == 0) atomicAdd(&y[(size_t)rt * DI + d], pv + uv * Dv);
    }
}

__global__ __launch_bounds__(256) void combine_kernel(
    float* __restrict__ y, const float* __restrict__ xr)
{
    int idx = blockIdx.x * 256 + threadIdx.x;
    int d = idx & (DI - 1);
    int t = idx >> 11;
    float r = xr[(size_t)t * 4096 + DI + d];
    y[idx] = y[idx] * 0.5f * silu_f(r);
}

extern "C" void kernel_launch(void* const* d_in, const int* in_sizes, int n_in,
                              void* d_out, int out_size, void* d_ws, size_t ws_size,
                              hipStream_t stream)
{
    const float* x      = (const float*)d_in[0];
    const float* W_in   = (const float*)d_in[1];
    const float* W_conv = (const float*)d_in[2];
    const float* b_conv = (const float*)d_in[3];
    const float* W_out  = (const float*)d_in[4];
    const float* fA_log = (const float*)d_in[5];
    const float* fD     = (const float*)d_in[6];
    const float* fWx    = (const float*)d_in[7];
    const float* fWdt   = (const float*)d_in[8];
    const float* fbdt   = (const float*)d_in[9];
    const float* bA_log = (const float*)d_in[10];
    const float* bD     = (const float*)d_in[11];
    const float* bWx    = (const float*)d_in[12];
    const float* bWdt   = (const float*)d_in[13];
    const float* bbdt   = (const float*)d_in[14];

    char* ws = (char*)d_ws;
    const size_t MB = 1ull << 20;
    float* xr    = (float*)(ws);                 // [0,32M)
    float* u     = (float*)(ws + 32*MB);         // [32,48M)
    float* dbc   = (float*)(ws + 48*MB);         // [48,49.5M)
    // GEMM1 split temps (dead after GEMM1), aliased in [50,82M):
    unsigned short* xh  = (unsigned short*)(ws + 50*MB);   // 4M
    unsigned short* xl  = (unsigned short*)(ws + 54*MB);   // 4M
    unsigned short* wih = (unsigned short*)(ws + 58*MB);   // 8M
    unsigned short* wil = (unsigned short*)(ws + 66*MB);   // 8M
    float* part  = (float*)(ws + 50*MB);         // [50,62M) alias, after GEMM1
    float* delta = (float*)(ws + 50*MB);         // [50,82M) alias, after dbc
    float* y     = (float*)(ws + 82*MB);         // [82,98M)
    float* Pb    = (float*)(ws + 98*MB);         // [98,102M)
    float* Hb    = (float*)(ws + 102*MB);        // [102,106M)
    // GEMM_out split temps (written after pass3, delta dead), alias [50,74M):
    unsigned short* yh  = (unsigned short*)(ws + 50*MB);   // 8M
    unsigned short* yl  = (unsigned short*)(ws + 58*MB);   // 8M
    unsigned short* woh = (unsigned short*)(ws + 66*MB);   // 4M
    unsigned short* wol = (unsigned short*)(ws + 70*MB);   // 4M
    float* out   = (float*)d_out;

    // 0. split x and W_in to bf16 hi/lo
    split_kernel<<<(T_TOK * DM / 4 + 255) / 256, 256, 0, stream>>>(x, xh, xl, T_TOK * DM / 4);
    split_kernel<<<(2 * DI * DM / 4 + 255) / 256, 256, 0, stream>>>(W_in, wih, wil, 2 * DI * DM / 4);

    // 1. xr = x @ W_in^T   (M=2048, N=4096, K=1024) — split-bf16 MFMA
    mgemm128<0><<<dim3(4096 / 128, 2048 / 128, 1), 256, 0, stream>>>(
        xh, xl, DM, wih, wil, DM, xr, 4096, DM);

    // 2. u = silu(causal_dwconv(xr[:, :2048]))
    conv_silu_kernel<<<(T_TOK * DI) / 256, 256, 0, stream>>>(xr, W_conv, b_conv, u);

    // 3. dbc[dir] = u @ Wx[dir]^T
    dbc_partial_kernel<<<dim3(32, 8, 2), 256, 0, stream>>>(u, fWx, bWx, part);
    dbc_reduce_kernel<<<(2 * T_TOK * E96) / 256, 256, 0, stream>>>(part, dbc);

    // 4. delta[dir] = softplus(dt @ Wdt^T + bdt)
    sgemm128<1><<<dim3(2048/128, 2048/128), 256, 0, stream>>>(
        dbc, 96, fWdt, 64, delta, 2048, 64, fbdt);
    sgemm128<1><<<dim3(2048/128, 2048/128), 256, 0, stream>>>(
        dbc + (size_t)T_TOK * E96, 96, bWdt, 64, delta + (size_t)T_TOK * DI, 2048, 64, bbdt);

    // 5. chunked scan (3 passes), both dirs accumulate into y
    scan_pass1<<<dim3(DI / 16, NCH, 4), 256, 0, stream>>>(
        u, delta, dbc, fA_log, bA_log, Pb, Hb);
    scan_pass2<<<(4 * DI * DS) / 256, 256, 0, stream>>>(Pb, Hb);
    hipMemsetAsync(y, 0, (size_t)T_TOK * DI * sizeof(float), stream);
    scan_pass3<<<dim3(DI / 16, NCH, 4), 256, 0, stream>>>(
        u, delta, dbc, fA_log, fD, bA_log, bD, Pb, y);

    // 6. y = (y_fwd + y_rev) * 0.5 * silu(res)
    combine_kernel<<<(T_TOK * DI) / 256, 256, 0, stream>>>(y, xr);

    // 7. out = y @ W_out^T  (M=2048, N=1024, K=2048) — split-bf16 MFMA, split-K=2
    split_kernel<<<(T_TOK * DI / 4 + 255) / 256, 256, 0, stream>>>(y, yh, yl, T_TOK * DI / 4);
    split_kernel<<<(DM * DI / 4 + 255) / 256, 256, 0, stream>>>(W_out, woh, wol, DM * DI / 4);
    hipMemsetAsync(out, 0, (size_t)T_TOK * DM * sizeof(float), stream);
    mgemm128<2><<<dim3(1024 / 128, 2048 / 128, 2), 256, 0, stream>>>(
        yh, yl, DI, woh, wol, DI, out, DM, DI);
}